// Round 4
// baseline (154.675 us; speedup 1.0000x reference)
//
#include <hip/hip_runtime.h>
#include <hip/hip_bf16.h>

#define SQi  2048
#define SBHi 4096            // element stride for s index: B*NH*HN
#define SCALE 0.08838834764831845f   // 1/sqrt(128)
#define PP   72              // P_lds pitch (shorts)

typedef __attribute__((ext_vector_type(4))) float f32x4;
typedef __attribute__((ext_vector_type(8))) short bf16x8;

__device__ __forceinline__ short f2bf(float f) {
    __hip_bfloat16 h = __float2bfloat16(f);   // single v_cvt (RNE) per guide m240
    return *reinterpret_cast<short*>(&h);
}

// ---- fused pre-pass: K,V fp32 [s][b][h][d] -> fragment-ordered bf16 ----
// KF[bh][t16][kk][lane][8]: frag(t16,kk)=16 kv x 32 d; lane(l15=kv, lhi=d-chunk)
// VF[bh][t32][nn][lane][8]: frag(t32,nn)=32 kv x 16 d; lane(l15=d,  lhi=kv-chunk)
__global__ __launch_bounds__(256)
void conv_kv(const float* __restrict__ K, const float* __restrict__ V,
             short* __restrict__ KF, short* __restrict__ VF) {
    int g = (int)blockIdx.x * 256 + (int)threadIdx.x;   // 2^21 threads
    if (g < (1 << 20)) {
        const int lane = g & 63, kk = (g >> 6) & 3, t16 = (g >> 8) & 127, bh = g >> 15;
        const int s = t16 * 16 + (lane & 15);
        const int d = kk * 32 + (lane >> 4) * 8;
        const float* in = K + (size_t)s * SBHi + (size_t)(bh >> 4) * 2048 + (bh & 15) * 128 + d;
        f32x4 a = *(const f32x4*)in;
        f32x4 b = *(const f32x4*)(in + 4);
        bf16x8 h;
        #pragma unroll
        for (int i = 0; i < 4; ++i) { h[i] = f2bf(a[i]); h[4 + i] = f2bf(b[i]); }
        *(bf16x8*)(KF + (size_t)g * 8) = h;
    } else {
        g -= (1 << 20);
        const int lane = g & 63, nn = (g >> 6) & 7, t32 = (g >> 9) & 63, bh = g >> 15;
        const int s = t32 * 32 + (lane >> 4) * 8;
        const int d = nn * 16 + (lane & 15);
        const float* in = V + (size_t)s * SBHi + (size_t)(bh >> 4) * 2048 + (bh & 15) * 128 + d;
        bf16x8 h;
        #pragma unroll
        for (int e = 0; e < 8; ++e) h[e] = f2bf(in[(size_t)e * SBHi]);
        *(bf16x8*)(VF + (size_t)g * 8) = h;
    }
}

// ---- main attention: 32-row paired q-tiles, 4 blocks/CU, barrier-free ----
__global__ __launch_bounds__(256, 4)
void attn_fwd4(const float* __restrict__ Q, const short* __restrict__ KF,
               const short* __restrict__ VF, float* __restrict__ O) {
    __shared__ __align__(16) short P_lds[4][16 * PP];

    const int bid = (int)blockIdx.x;          // 1024 blocks
    const int xcd = bid & 7, j = bid >> 3;    // j in [0,128)
    const int bh  = xcd + 8 * (j >> 5);       // 4 bh per XCD
    const int p   = j & 31;                   // pair id over 32-row tiles

    const size_t bh_q = (size_t)(bh >> 4) * 2048 + (size_t)(bh & 15) * 128;
    const short* KFb = KF + (size_t)bh * 262144;
    const short* VFb = VF + (size_t)bh * 262144;

    const int t = (int)threadIdx.x;
    const int lane = t & 63, wv = t >> 6, l15 = lane & 15, lhi = lane >> 4;

    // waves 0-1 -> 32-row tile p; waves 2-3 -> tile 63-p  (uniform total work)
    const int qt32  = (wv < 2) ? p : 63 - p;
    const int row0w = qt32 * 32 + (wv & 1) * 16;     // wave's first q-row
    const int dt    = (row0w + 15) >> 6;             // wave's diagonal KV tile

    // Q fragments (A operand), scale folded in
    bf16x8 q_frag[4];
    {
        const float* qp = Q + (size_t)(row0w + l15) * SBHi + bh_q + lhi * 8;
        #pragma unroll
        for (int kk = 0; kk < 4; ++kk) {
            f32x4 a = *(const f32x4*)(qp + kk * 32);
            f32x4 b = *(const f32x4*)(qp + kk * 32 + 4);
            #pragma unroll
            for (int i = 0; i < 4; ++i) {
                q_frag[kk][i]     = f2bf(a[i] * SCALE);
                q_frag[kk][4 + i] = f2bf(b[i] * SCALE);
            }
        }
    }

    float m_r[4], l_part[4];
    #pragma unroll
    for (int r = 0; r < 4; ++r) { m_r[r] = -1e30f; l_part[r] = 0.f; }
    f32x4 o_acc[8];
    #pragma unroll
    for (int nn = 0; nn < 8; ++nn) o_acc[nn] = (f32x4){0.f, 0.f, 0.f, 0.f};

    const int row0 = row0w + lhi * 4;                // lane's first of 4 rows

    for (int it = 0; it <= dt; ++it) {
        // ---- S = Q K^T : 16 rows x 64 cols, coalesced K fragment loads ----
        f32x4 s_acc[4];
        #pragma unroll
        for (int kb = 0; kb < 4; ++kb) s_acc[kb] = (f32x4){0.f, 0.f, 0.f, 0.f};
        const short* kbase = KFb + (size_t)it * 8192 + lane * 8;
        #pragma unroll
        for (int kb = 0; kb < 4; ++kb) {
            #pragma unroll
            for (int kk = 0; kk < 4; ++kk) {
                bf16x8 kfr = *(const bf16x8*)(kbase + (kb * 4 + kk) * 512);
                s_acc[kb] = __builtin_amdgcn_mfma_f32_16x16x32_bf16(q_frag[kk], kfr, s_acc[kb], 0, 0, 0);
            }
        }

        // ---- first-half V fragments issued early: latency hides under softmax ----
        const short* vbase = VFb + (size_t)it * 8192 + lane * 8;
        bf16x8 vfr0[8];
        #pragma unroll
        for (int nn = 0; nn < 8; ++nn) vfr0[nn] = *(const bf16x8*)(vbase + nn * 512);

        const bool need_mask = (it == dt);

        // ---- online softmax (16-lane groups per row), deferred l-reduce ----
        #pragma unroll
        for (int r = 0; r < 4; ++r) {
            const int rg = row0 + r;
            float s0 = s_acc[0][r];
            float s1 = s_acc[1][r];
            float s2 = s_acc[2][r];
            float s3 = s_acc[3][r];
            if (need_mask) {
                const int c = it * 64 + l15;
                if (c      > rg) s0 = -1e30f;
                if (c + 16 > rg) s1 = -1e30f;
                if (c + 32 > rg) s2 = -1e30f;
                if (c + 48 > rg) s3 = -1e30f;
            }
            float mx = fmaxf(fmaxf(s0, s1), fmaxf(s2, s3));
            #pragma unroll
            for (int m = 1; m < 16; m <<= 1) mx = fmaxf(mx, __shfl_xor(mx, m));
            if (mx > m_r[r] + 8.f) {            // defer-max (T13)
                const float corr = __expf(m_r[r] - mx);
                m_r[r] = mx;
                l_part[r] *= corr;
                #pragma unroll
                for (int nn = 0; nn < 8; ++nn) o_acc[nn][r] *= corr;
            }
            const float mm = m_r[r];
            const float p0 = __expf(s0 - mm);
            const float p1 = __expf(s1 - mm);
            const float p2 = __expf(s2 - mm);
            const float p3 = __expf(s3 - mm);
            l_part[r] += (p0 + p1) + (p2 + p3);
            const int rl = (lhi * 4 + r) * PP;
            P_lds[wv][rl + l15]      = f2bf(p0);
            P_lds[wv][rl + 16 + l15] = f2bf(p1);
            P_lds[wv][rl + 32 + l15] = f2bf(p2);
            P_lds[wv][rl + 48 + l15] = f2bf(p3);
        }

        // ---- O += P V : second-half V loads hide under first-half MFMAs ----
        bf16x8 pa0 = *(const bf16x8*)&P_lds[wv][l15 * PP + lhi * 8];
        bf16x8 pa1 = *(const bf16x8*)&P_lds[wv][l15 * PP + 32 + lhi * 8];
        bf16x8 vfr1[8];
        #pragma unroll
        for (int nn = 0; nn < 8; ++nn) vfr1[nn] = *(const bf16x8*)(vbase + (8 + nn) * 512);
        #pragma unroll
        for (int nn = 0; nn < 8; ++nn)
            o_acc[nn] = __builtin_amdgcn_mfma_f32_16x16x32_bf16(pa0, vfr0[nn], o_acc[nn], 0, 0, 0);
        #pragma unroll
        for (int nn = 0; nn < 8; ++nn)
            o_acc[nn] = __builtin_amdgcn_mfma_f32_16x16x32_bf16(pa1, vfr1[nn], o_acc[nn], 0, 0, 0);
    }

    // ---- epilogue: reduce l across the 16-lane group, then O / l ----
    #pragma unroll
    for (int r = 0; r < 4; ++r) {
        float ls = l_part[r];
        #pragma unroll
        for (int m = 1; m < 16; m <<= 1) ls += __shfl_xor(ls, m);
        const float inv = 1.0f / ls;
        float* op = O + (size_t)(row0 + r) * SBHi + bh_q + l15;
        #pragma unroll
        for (int nn = 0; nn < 8; ++nn) op[nn * 16] = o_acc[nn][r] * inv;
    }
}

extern "C" void kernel_launch(void* const* d_in, const int* in_sizes, int n_in,
                              void* d_out, int out_size, void* d_ws, size_t ws_size,
                              hipStream_t stream) {
    const float* q = (const float*)d_in[0];
    const float* k = (const float*)d_in[1];
    const float* v = (const float*)d_in[2];
    float* out = (float*)d_out;

    short* KF = (short*)d_ws;                       // 16.78 MB
    short* VF = KF + (size_t)32 * 262144;           // +16.78 MB (total ~33.5 MB)

    conv_kv<<<8192, 256, 0, stream>>>(k, v, KF, VF);
    attn_fwd4<<<1024, 256, 0, stream>>>(q, KF, VF, out);
}

// Round 5
// 109.025 us; speedup vs baseline: 1.4187x; 1.4187x over previous
//
#include <hip/hip_runtime.h>
#include <hip/hip_bf16.h>

#define SQi  2048
#define SBHi 4096            // element stride for s index: B*NH*HN
#define SCALE 0.08838834764831845f   // 1/sqrt(128)
#define PP   72              // P_lds pitch (shorts)

typedef __attribute__((ext_vector_type(4))) float f32x4;
typedef __attribute__((ext_vector_type(8))) short bf16x8;

__device__ __forceinline__ short f2bf(float f) {
    __hip_bfloat16 h = __float2bfloat16(f);
    return *reinterpret_cast<short*>(&h);
}

// ---- fused pre-pass: K,V fp32 [s][b][h][d] -> fragment-ordered bf16 ----
// KF[bh][t16][kk][lane][8]: frag(t16,kk)=16 kv x 32 d; lane(l15=kv, lhi=d-chunk)
// VF[bh][t32][nn][lane][8]: frag(t32,nn)=32 kv x 16 d; lane(l15=d,  lhi=kv-chunk)
__global__ __launch_bounds__(256)
void conv_kv(const float* __restrict__ K, const float* __restrict__ V,
             short* __restrict__ KF, short* __restrict__ VF) {
    int g = (int)blockIdx.x * 256 + (int)threadIdx.x;   // 2^21 threads
    if (g < (1 << 20)) {
        const int lane = g & 63, kk = (g >> 6) & 3, t16 = (g >> 8) & 127, bh = g >> 15;
        const int s = t16 * 16 + (lane & 15);
        const int d = kk * 32 + (lane >> 4) * 8;
        const float* in = K + (size_t)s * SBHi + (size_t)(bh >> 4) * 2048 + (bh & 15) * 128 + d;
        f32x4 a = *(const f32x4*)in;
        f32x4 b = *(const f32x4*)(in + 4);
        bf16x8 h;
        #pragma unroll
        for (int i = 0; i < 4; ++i) { h[i] = f2bf(a[i]); h[4 + i] = f2bf(b[i]); }
        *(bf16x8*)(KF + (size_t)g * 8) = h;
    } else {
        g -= (1 << 20);
        const int lane = g & 63, nn = (g >> 6) & 7, t32 = (g >> 9) & 63, bh = g >> 15;
        const int s = t32 * 32 + (lane >> 4) * 8;
        const int d = nn * 16 + (lane & 15);
        const float* in = V + (size_t)s * SBHi + (size_t)(bh >> 4) * 2048 + (bh & 15) * 128 + d;
        bf16x8 h;
        #pragma unroll
        for (int e = 0; e < 8; ++e) h[e] = f2bf(in[(size_t)e * SBHi]);
        *(bf16x8*)(VF + (size_t)g * 8) = h;
    }
}

// ---- main attention: uniform paired q-tiles, K register double-buffer pipeline ----
__global__ __launch_bounds__(256, 2)
void attn_fwd5(const float* __restrict__ Q, const short* __restrict__ KF,
               const short* __restrict__ VF, float* __restrict__ O) {
    __shared__ __align__(16) short P_lds[4][16 * PP];

    const int bid = (int)blockIdx.x;          // 512 blocks
    const int xcd = bid & 7, j = bid >> 3;    // j in [0,64)
    const int bh  = xcd + 8 * (j >> 4);       // 4 bh per XCD -> KF+VF ~4MB ~ one L2
    const int pr  = j & 15;                   // pair id: q-tiles (pr, 31-pr), 33 tiles uniform

    const size_t bh_q = (size_t)(bh >> 4) * 2048 + (size_t)(bh & 15) * 128;
    const short* KFb = KF + (size_t)bh * 262144;
    const short* VFb = VF + (size_t)bh * 262144;

    const int t = (int)threadIdx.x;
    const int lane = t & 63, wv = t >> 6, l15 = lane & 15, lhi = lane >> 4;

    for (int half = 0; half < 2; ++half) {
        const int qt = half ? (31 - pr) : pr;

        // Q fragments (A operand), scale folded in
        bf16x8 q_frag[4];
        {
            const int qrow = qt * 64 + wv * 16 + l15;
            const float* qp = Q + (size_t)qrow * SBHi + bh_q + lhi * 8;
            #pragma unroll
            for (int kk = 0; kk < 4; ++kk) {
                f32x4 a = *(const f32x4*)(qp + kk * 32);
                f32x4 b = *(const f32x4*)(qp + kk * 32 + 4);
                #pragma unroll
                for (int i = 0; i < 4; ++i) {
                    q_frag[kk][i]     = f2bf(a[i] * SCALE);
                    q_frag[kk][4 + i] = f2bf(b[i] * SCALE);
                }
            }
        }

        float m_r[4], l_part[4];
        #pragma unroll
        for (int r = 0; r < 4; ++r) { m_r[r] = -1e30f; l_part[r] = 0.f; }
        f32x4 o_acc[8];
        #pragma unroll
        for (int nn = 0; nn < 8; ++nn) o_acc[nn] = (f32x4){0.f, 0.f, 0.f, 0.f};

        const int row0 = qt * 64 + wv * 16 + lhi * 4;

        // ---- K register double-buffer: prologue loads tile 0 ----
        bf16x8 ka[16], kb[16];
        {
            const short* k0 = KFb + lane * 8;
            #pragma unroll
            for (int f = 0; f < 16; ++f) ka[f] = *(const bf16x8*)(k0 + f * 512);
        }

        auto body = [&](bf16x8 (&kc)[16], bf16x8 (&kn)[16], int it) {
            // ---- S = Q K^T from current K buffer (registers, no wait on loads) ----
            f32x4 s_acc[4];
            #pragma unroll
            for (int kb4 = 0; kb4 < 4; ++kb4) s_acc[kb4] = (f32x4){0.f, 0.f, 0.f, 0.f};
            #pragma unroll
            for (int kb4 = 0; kb4 < 4; ++kb4) {
                #pragma unroll
                for (int kk = 0; kk < 4; ++kk)
                    s_acc[kb4] = __builtin_amdgcn_mfma_f32_16x16x32_bf16(q_frag[kk], kc[kb4 * 4 + kk], s_acc[kb4], 0, 0, 0);
            }

            // ---- V(it) loads: needed at PV, hidden under softmax ----
            const short* vbase = VFb + (size_t)it * 8192 + lane * 8;
            bf16x8 vfr0[8];
            #pragma unroll
            for (int nn = 0; nn < 8; ++nn) vfr0[nn] = *(const bf16x8*)(vbase + nn * 512);

            // ---- prefetch K(it+1): needed next iteration, hidden under softmax+PV ----
            {
                const int itn = (it + 1 <= qt) ? it + 1 : qt;   // clamp (last iter: dead load)
                const short* knb = KFb + (size_t)itn * 8192 + lane * 8;
                #pragma unroll
                for (int f = 0; f < 16; ++f) kn[f] = *(const bf16x8*)(knb + f * 512);
            }

            const bool need_mask = (it == qt);

            // ---- online softmax (16-lane groups per row), deferred l-reduce ----
            #pragma unroll
            for (int r = 0; r < 4; ++r) {
                const int rg = row0 + r;
                float s0 = s_acc[0][r];
                float s1 = s_acc[1][r];
                float s2 = s_acc[2][r];
                float s3 = s_acc[3][r];
                if (need_mask) {
                    const int c = it * 64 + l15;
                    if (c      > rg) s0 = -1e30f;
                    if (c + 16 > rg) s1 = -1e30f;
                    if (c + 32 > rg) s2 = -1e30f;
                    if (c + 48 > rg) s3 = -1e30f;
                }
                float mx = fmaxf(fmaxf(s0, s1), fmaxf(s2, s3));
                #pragma unroll
                for (int m = 1; m < 16; m <<= 1) mx = fmaxf(mx, __shfl_xor(mx, m));
                if (mx > m_r[r] + 8.f) {            // defer-max (T13)
                    const float corr = __expf(m_r[r] - mx);
                    m_r[r] = mx;
                    l_part[r] *= corr;
                    #pragma unroll
                    for (int nn = 0; nn < 8; ++nn) o_acc[nn][r] *= corr;
                }
                const float mm = m_r[r];
                const float p0 = __expf(s0 - mm);
                const float p1 = __expf(s1 - mm);
                const float p2 = __expf(s2 - mm);
                const float p3 = __expf(s3 - mm);
                l_part[r] += (p0 + p1) + (p2 + p3);
                const int rl = (lhi * 4 + r) * PP;
                P_lds[wv][rl + l15]      = f2bf(p0);
                P_lds[wv][rl + 16 + l15] = f2bf(p1);
                P_lds[wv][rl + 32 + l15] = f2bf(p2);
                P_lds[wv][rl + 48 + l15] = f2bf(p3);
            }

            // ---- O += P V : second-half V loads hide under first-half MFMAs ----
            bf16x8 pa0 = *(const bf16x8*)&P_lds[wv][l15 * PP + lhi * 8];
            bf16x8 pa1 = *(const bf16x8*)&P_lds[wv][l15 * PP + 32 + lhi * 8];
            bf16x8 vfr1[8];
            #pragma unroll
            for (int nn = 0; nn < 8; ++nn) vfr1[nn] = *(const bf16x8*)(vbase + (8 + nn) * 512);
            #pragma unroll
            for (int nn = 0; nn < 8; ++nn)
                o_acc[nn] = __builtin_amdgcn_mfma_f32_16x16x32_bf16(pa0, vfr0[nn], o_acc[nn], 0, 0, 0);
            #pragma unroll
            for (int nn = 0; nn < 8; ++nn)
                o_acc[nn] = __builtin_amdgcn_mfma_f32_16x16x32_bf16(pa1, vfr1[nn], o_acc[nn], 0, 0, 0);
        };

        int it = 0;
        for (; it + 1 <= qt; it += 2) {         // ping-pong: static buffer roles
            body(ka, kb, it);
            body(kb, ka, it + 1);
        }
        if (it <= qt) body(ka, kb, it);         // tail (odd trip count)

        // ---- epilogue: reduce l across the 16-lane group, then O / l ----
        #pragma unroll
        for (int r = 0; r < 4; ++r) {
            float ls = l_part[r];
            #pragma unroll
            for (int m = 1; m < 16; m <<= 1) ls += __shfl_xor(ls, m);
            const float inv = 1.0f / ls;
            float* op = O + (size_t)(row0 + r) * SBHi + bh_q + l15;
            #pragma unroll
            for (int nn = 0; nn < 8; ++nn) op[nn * 16] = o_acc[nn][r] * inv;
        }
    }
}

extern "C" void kernel_launch(void* const* d_in, const int* in_sizes, int n_in,
                              void* d_out, int out_size, void* d_ws, size_t ws_size,
                              hipStream_t stream) {
    const float* q = (const float*)d_in[0];
    const float* k = (const float*)d_in[1];
    const float* v = (const float*)d_in[2];
    float* out = (float*)d_out;

    short* KF = (short*)d_ws;                       // 16.78 MB
    short* VF = KF + (size_t)32 * 262144;           // +16.78 MB (total ~33.5 MB)

    conv_kv<<<8192, 256, 0, stream>>>(k, v, KF, VF);
    attn_fwd5<<<512, 256, 0, stream>>>(q, KF, VF, out);
}